// Round 2
// baseline (238.516 us; speedup 1.0000x reference)
//
#include <hip/hip_runtime.h>
#include <hip/hip_bf16.h>
#include <stdint.h>

#define B_  4
#define S_  2048
#define BS_ (B_ * S_)   // 8192 tokens
#define D_  1024
#define O_  1024
#define H_  8

#define BM 128
#define BN 128
#define BK 64

typedef unsigned short u16;
typedef __attribute__((ext_vector_type(8))) short     short8;
typedef __attribute__((ext_vector_type(8))) unsigned short ushort8v;
typedef __attribute__((ext_vector_type(4))) float     f32x4;

__device__ __forceinline__ u16 f2bf(float f) {
  unsigned u = __float_as_uint(f);
  unsigned r = (u + 0x7fffu + ((u >> 16) & 1u)) >> 16;
  return (u16)r;
}

// async global->LDS, 16B per lane; LDS dest is wave-uniform base + lane*16
#define GLOAD16(gp, lp)                                                        \
  __builtin_amdgcn_global_load_lds(                                            \
      (const __attribute__((address_space(1))) void*)(gp),                     \
      (__attribute__((address_space(3))) void*)(lp), 16, 0, 0)

// ---------------------------------------------------------------------------
// Kernel 1: gates (f32, one wave per token) + x -> bf16 conversion
// ---------------------------------------------------------------------------
__global__ __launch_bounds__(256) void gate_conv_kernel(
    const float* __restrict__ x, const float* __restrict__ gate_w,
    const float* __restrict__ gate_b, u16* __restrict__ x_bf,
    float* __restrict__ g_out) {
  const int wave  = threadIdx.x >> 6;
  const int lane  = threadIdx.x & 63;
  const int token = blockIdx.x * 4 + wave;   // BS_/4 blocks
  const float* xr = x + (size_t)token * D_;
  const int d0 = lane * 16;                  // 64 lanes * 16 = 1024 elems

  float4 xv[4];
#pragma unroll
  for (int i = 0; i < 4; ++i) xv[i] = *(const float4*)(xr + d0 + i * 4);

  ushort8v lo, hi;
#pragma unroll
  for (int i = 0; i < 2; ++i) {
    lo[i * 4 + 0] = f2bf(xv[i].x); lo[i * 4 + 1] = f2bf(xv[i].y);
    lo[i * 4 + 2] = f2bf(xv[i].z); lo[i * 4 + 3] = f2bf(xv[i].w);
    hi[i * 4 + 0] = f2bf(xv[2 + i].x); hi[i * 4 + 1] = f2bf(xv[2 + i].y);
    hi[i * 4 + 2] = f2bf(xv[2 + i].z); hi[i * 4 + 3] = f2bf(xv[2 + i].w);
  }
  *(ushort8v*)(x_bf + (size_t)token * D_ + d0) = lo;
  *(ushort8v*)(x_bf + (size_t)token * D_ + d0 + 8) = hi;

  float s[H_];
#pragma unroll
  for (int h = 0; h < H_; ++h) {
    const float* gw = gate_w + h * D_ + d0;
    float a = 0.f;
#pragma unroll
    for (int i = 0; i < 4; ++i) {
      float4 w = *(const float4*)(gw + i * 4);
      a += xv[i].x * w.x + xv[i].y * w.y + xv[i].z * w.z + xv[i].w * w.w;
    }
    s[h] = a;
  }
#pragma unroll
  for (int h = 0; h < H_; ++h) {
#pragma unroll
    for (int off = 32; off > 0; off >>= 1) s[h] += __shfl_xor(s[h], off);
    s[h] += gate_b[h];
  }
  float m = s[0];
#pragma unroll
  for (int h = 1; h < H_; ++h) m = fmaxf(m, s[h]);
  float sum = 0.f;
#pragma unroll
  for (int h = 0; h < H_; ++h) { s[h] = expf(s[h] - m); sum += s[h]; }
  const float inv = 1.0f / sum;
#pragma unroll
  for (int h = 0; h < H_; ++h) s[h] *= inv;

  if (lane == 0) {
    float4 g0 = make_float4(s[0], s[1], s[2], s[3]);
    float4 g1 = make_float4(s[4], s[5], s[6], s[7]);
    *(float4*)(g_out + (size_t)token * H_)     = g0;
    *(float4*)(g_out + (size_t)token * H_ + 4) = g1;
  }
}

// ---------------------------------------------------------------------------
// Kernel 2: expert_w f32 -> bf16
// ---------------------------------------------------------------------------
__global__ __launch_bounds__(256) void convw_kernel(
    const float* __restrict__ w, u16* __restrict__ wb) {
  size_t i = ((size_t)blockIdx.x * 256 + threadIdx.x) * 8;
  float4 a = *(const float4*)(w + i);
  float4 b = *(const float4*)(w + i + 4);
  ushort8v v;
  v[0] = f2bf(a.x); v[1] = f2bf(a.y); v[2] = f2bf(a.z); v[3] = f2bf(a.w);
  v[4] = f2bf(b.x); v[5] = f2bf(b.y); v[6] = f2bf(b.z); v[7] = f2bf(b.w);
  *(ushort8v*)(wb + i) = v;
}

// ---------------------------------------------------------------------------
// Kernel 3: fused MoE GEMM.  out[r,c] = sum_h g[r,h]*(X[r,:]·W[h,c,:] + eb[h,c])
// 128x128 tile, BK=64, 8 waves (2x4 grid of 64x32 wave tiles),
// mfma_f32_16x16x32_bf16, global_load_lds width-16 staging, h-outer with
// per-h partial accumulator fold.  512 thr, 2 blk/CU -> 16 waves/CU.
// ---------------------------------------------------------------------------
__global__ __launch_bounds__(512, 4) void moe_gemm_kernel(
    const u16* __restrict__ Xb, const u16* __restrict__ Wb,
    const float* __restrict__ g, const float* __restrict__ eb,
    float* __restrict__ out) {
  __shared__ __align__(16) u16 As[BM * BK];  // [128][64] linear (row = 128B)
  __shared__ __align__(16) u16 Bs[BN * BK];
  __shared__ float gs[BM][H_];
  __shared__ float ebs[H_][BN];

  const int tid  = threadIdx.x;
  const int wave = tid >> 6;
  const int lane = tid & 63;

  // bijective XCD swizzle: nwg = 512, 512 % 8 == 0
  const int bx  = blockIdx.x;
  const int swz = (bx & 7) * 64 + (bx >> 3);
  const int row0 = (swz >> 3) * BM;  // 64 row blocks
  const int col0 = (swz & 7) * BN;   // 8 col blocks

  for (int i = tid; i < BM * H_; i += 512)
    ((float*)gs)[i] = g[(size_t)row0 * H_ + i];
  for (int i = tid; i < H_ * BN; i += 512)
    ebs[i / BN][i % BN] = eb[(i / BN) * O_ + col0 + (i % BN)];

  const int wm = wave >> 2;  // 0..1  (64 rows)
  const int wn = wave & 3;   // 0..3  (32 cols)

  // staging: per issue, wave w covers 8 rows [w*8, w*8+8); 2 issues (+64 rows)
  const int st_row = wave * 8 + (lane >> 3);
  const int st_col = (lane & 7) * 8;
  const u16* a_src = Xb + (size_t)(row0 + st_row) * D_ + st_col;
  u16* const as_b0 = &As[(wave * 8) * BK];
  u16* const as_b1 = &As[(64 + wave * 8) * BK];
  u16* const bs_b0 = &Bs[(wave * 8) * BK];
  u16* const bs_b1 = &Bs[(64 + wave * 8) * BK];

  // LDS fragment read offsets (ushort elements)
  const int a_rd = (wm * 64 + (lane & 15)) * BK + (lane >> 4) * 8;
  const int b_rd = (wn * 32 + (lane & 15)) * BK + (lane >> 4) * 8;

  const f32x4 zero4 = {0.f, 0.f, 0.f, 0.f};
  f32x4 acc[4][2];
#pragma unroll
  for (int i = 0; i < 4; ++i)
#pragma unroll
    for (int j = 0; j < 2; ++j) acc[i][j] = zero4;

  __syncthreads();  // gs/ebs ready

  for (int h = 0; h < H_; ++h) {
    const u16* b_src = Wb + ((size_t)h * O_ + col0 + st_row) * D_ + st_col;

    f32x4 part[4][2];
#pragma unroll
    for (int i = 0; i < 4; ++i)
#pragma unroll
      for (int j = 0; j < 2; ++j) part[i][j] = zero4;

    for (int kt = 0; kt < D_ / BK; ++kt) {
      const int koff = kt * BK;
      GLOAD16(a_src + koff, as_b0);
      GLOAD16(a_src + (size_t)64 * D_ + koff, as_b1);
      GLOAD16(b_src + koff, bs_b0);
      GLOAD16(b_src + (size_t)64 * D_ + koff, bs_b1);
      asm volatile("s_waitcnt vmcnt(0)" ::: "memory");
      __syncthreads();

#pragma unroll
      for (int kk = 0; kk < 2; ++kk) {
        short8 af[4], bfr[2];
#pragma unroll
        for (int fm = 0; fm < 4; ++fm)
          af[fm] = *(const short8*)&As[a_rd + fm * 16 * BK + kk * 32];
#pragma unroll
        for (int fn = 0; fn < 2; ++fn)
          bfr[fn] = *(const short8*)&Bs[b_rd + fn * 16 * BK + kk * 32];
#pragma unroll
        for (int fm = 0; fm < 4; ++fm)
#pragma unroll
          for (int fn = 0; fn < 2; ++fn)
            part[fm][fn] = __builtin_amdgcn_mfma_f32_16x16x32_bf16(
                af[fm], bfr[fn], part[fm][fn], 0, 0, 0);
      }
      __syncthreads();
    }

    // fold: acc += g[r,h] * (part + eb[h,c])
    float ebv[2];
#pragma unroll
    for (int fn = 0; fn < 2; ++fn)
      ebv[fn] = ebs[h][wn * 32 + fn * 16 + (lane & 15)];
#pragma unroll
    for (int fm = 0; fm < 4; ++fm) {
#pragma unroll
      for (int j = 0; j < 4; ++j) {
        const float gg = gs[wm * 64 + fm * 16 + (lane >> 4) * 4 + j][h];
#pragma unroll
        for (int fn = 0; fn < 2; ++fn)
          acc[fm][fn][j] += gg * (part[fm][fn][j] + ebv[fn]);
      }
    }
  }

  // epilogue: C/D layout col = lane&15, row = (lane>>4)*4 + j
  const int crow = row0 + wm * 64 + (lane >> 4) * 4;
  const int ccol = col0 + wn * 32 + (lane & 15);
#pragma unroll
  for (int fm = 0; fm < 4; ++fm)
#pragma unroll
    for (int fn = 0; fn < 2; ++fn)
#pragma unroll
      for (int j = 0; j < 4; ++j)
        out[(size_t)(crow + fm * 16 + j) * O_ + (ccol + fn * 16)] = acc[fm][fn][j];
}

// ---------------------------------------------------------------------------
extern "C" void kernel_launch(void* const* d_in, const int* in_sizes, int n_in,
                              void* d_out, int out_size, void* d_ws,
                              size_t ws_size, hipStream_t stream) {
  const float* x   = (const float*)d_in[0];
  const float* gw  = (const float*)d_in[1];
  const float* gb  = (const float*)d_in[2];
  const float* ew  = (const float*)d_in[3];
  const float* ebp = (const float*)d_in[4];
  float* out = (float*)d_out;

  u16*   x_bf = (u16*)d_ws;                                            // 16 MB
  u16*   w_bf = (u16*)((char*)d_ws + (size_t)BS_ * D_ * 2);            // 16 MB
  float* gbuf = (float*)((char*)d_ws + (size_t)BS_ * D_ * 2 +
                         (size_t)H_ * O_ * D_ * 2);                    // 256 KB

  gate_conv_kernel<<<BS_ / 4, 256, 0, stream>>>(x, gw, gb, x_bf, gbuf);
  convw_kernel<<<(H_ * O_ * D_) / 2048, 256, 0, stream>>>(ew, w_bf);
  moe_gemm_kernel<<<(BS_ / BM) * (O_ / BN), 512, 0, stream>>>(x_bf, w_bf, gbuf,
                                                              ebp, out);
}

// Round 3
// 196.029 us; speedup vs baseline: 1.2167x; 1.2167x over previous
//
#include <hip/hip_runtime.h>
#include <hip/hip_bf16.h>
#include <stdint.h>

#define B_  4
#define S_  2048
#define BS_ (B_ * S_)   // 8192 tokens
#define D_  1024
#define O_  1024
#define H_  8

#define BM 256
#define BN 128
#define BK 64
#define NT 128          // K' tiles: (h,k) combined, 8*1024/64

typedef unsigned short u16;
typedef __attribute__((ext_vector_type(8))) short     short8;
typedef __attribute__((ext_vector_type(8))) unsigned short ushort8v;
typedef __attribute__((ext_vector_type(4))) float     f32x4;

__device__ __forceinline__ u16 f2bf(float f) {
  unsigned u = __float_as_uint(f);
  unsigned r = (u + 0x7fffu + ((u >> 16) & 1u)) >> 16;
  return (u16)r;
}

#define GLOAD16(gp, lp)                                                        \
  __builtin_amdgcn_global_load_lds(                                            \
      (const __attribute__((address_space(1))) void*)(gp),                     \
      (__attribute__((address_space(3))) void*)(lp), 16, 0, 0)

// ---------------------------------------------------------------------------
// Kernel 1: gates (f32, one wave per token) + x -> bf16 conversion
// ---------------------------------------------------------------------------
__global__ __launch_bounds__(256) void gate_conv_kernel(
    const float* __restrict__ x, const float* __restrict__ gate_w,
    const float* __restrict__ gate_b, u16* __restrict__ x_bf,
    float* __restrict__ g_out) {
  const int wave  = threadIdx.x >> 6;
  const int lane  = threadIdx.x & 63;
  const int token = blockIdx.x * 4 + wave;
  const float* xr = x + (size_t)token * D_;
  const int d0 = lane * 16;

  float4 xv[4];
#pragma unroll
  for (int i = 0; i < 4; ++i) xv[i] = *(const float4*)(xr + d0 + i * 4);

  ushort8v lo, hi;
#pragma unroll
  for (int i = 0; i < 2; ++i) {
    lo[i * 4 + 0] = f2bf(xv[i].x); lo[i * 4 + 1] = f2bf(xv[i].y);
    lo[i * 4 + 2] = f2bf(xv[i].z); lo[i * 4 + 3] = f2bf(xv[i].w);
    hi[i * 4 + 0] = f2bf(xv[2 + i].x); hi[i * 4 + 1] = f2bf(xv[2 + i].y);
    hi[i * 4 + 2] = f2bf(xv[2 + i].z); hi[i * 4 + 3] = f2bf(xv[2 + i].w);
  }
  *(ushort8v*)(x_bf + (size_t)token * D_ + d0) = lo;
  *(ushort8v*)(x_bf + (size_t)token * D_ + d0 + 8) = hi;

  float s[H_];
#pragma unroll
  for (int h = 0; h < H_; ++h) {
    const float* gw = gate_w + h * D_ + d0;
    float a = 0.f;
#pragma unroll
    for (int i = 0; i < 4; ++i) {
      float4 w = *(const float4*)(gw + i * 4);
      a += xv[i].x * w.x + xv[i].y * w.y + xv[i].z * w.z + xv[i].w * w.w;
    }
    s[h] = a;
  }
#pragma unroll
  for (int h = 0; h < H_; ++h) {
#pragma unroll
    for (int off = 32; off > 0; off >>= 1) s[h] += __shfl_xor(s[h], off);
    s[h] += gate_b[h];
  }
  float m = s[0];
#pragma unroll
  for (int h = 1; h < H_; ++h) m = fmaxf(m, s[h]);
  float sum = 0.f;
#pragma unroll
  for (int h = 0; h < H_; ++h) { s[h] = expf(s[h] - m); sum += s[h]; }
  const float inv = 1.0f / sum;
#pragma unroll
  for (int h = 0; h < H_; ++h) s[h] *= inv;

  if (lane == 0) {
    float4 g0 = make_float4(s[0], s[1], s[2], s[3]);
    float4 g1 = make_float4(s[4], s[5], s[6], s[7]);
    *(float4*)(g_out + (size_t)token * H_)     = g0;
    *(float4*)(g_out + (size_t)token * H_ + 4) = g1;
  }
}

// ---------------------------------------------------------------------------
// Kernel 2: expert_w f32 -> bf16
// ---------------------------------------------------------------------------
__global__ __launch_bounds__(256) void convw_kernel(
    const float* __restrict__ w, u16* __restrict__ wb) {
  size_t i = ((size_t)blockIdx.x * 256 + threadIdx.x) * 8;
  float4 a = *(const float4*)(w + i);
  float4 b = *(const float4*)(w + i + 4);
  ushort8v v;
  v[0] = f2bf(a.x); v[1] = f2bf(a.y); v[2] = f2bf(a.z); v[3] = f2bf(a.w);
  v[4] = f2bf(b.x); v[5] = f2bf(b.y); v[6] = f2bf(b.z); v[7] = f2bf(b.w);
  *(ushort8v*)(wb + i) = v;
}

// ---------------------------------------------------------------------------
// Kernel 3: fused MoE GEMM, 8-phase-style pipeline.
//   out[r,c] = sum_h g[r,h]*(X[r,:]·W[h,c,:] + eb[h,c])
// BM=256 x BN=128 tile, BK=64, 8 waves (2Mx4N, per-wave 128x32), grid=256
// (1 block/CU). K' = (h,k): 128 tiles, continuous 3-deep LDS ring with
// counted vmcnt(6), 2 phases/tile, T2 2-bit XOR swizzle, T5 setprio,
// g-fold every 16 tiles.
// ---------------------------------------------------------------------------
__global__ __launch_bounds__(512, 2) void moe_gemm_kernel(
    const u16* __restrict__ Xb, const u16* __restrict__ Wb,
    const float* __restrict__ g, const float* __restrict__ eb,
    float* __restrict__ out) {
  __shared__ __align__(16) u16 As[3][BM * BK];   // 3 x 32 KB
  __shared__ __align__(16) u16 Bs[3][BN * BK];   // 3 x 16 KB
  __shared__ float gs[H_][BM];                   // 8 KB, transposed
  __shared__ float ebs[H_][BN];                  // 4 KB

  const int tid  = threadIdx.x;
  const int wave = tid >> 6;
  const int lane = tid & 63;

  const int bx   = blockIdx.x;           // 256 blocks; bx&7 ~ XCD id
  const int row0 = (bx >> 3) * BM;       // 32 row tiles
  const int col0 = (bx & 7) * BN;        // 8 col tiles; W panel (2MB) L2-fits

  for (int i = tid; i < H_ * BM; i += 512) {
    int h = i >> 8, r = i & 255;
    gs[h][r] = g[(size_t)(row0 + r) * H_ + h];
  }
  for (int i = tid; i < H_ * BN; i += 512) {
    int h = i >> 7, c = i & 127;
    ebs[h][c] = eb[h * O_ + col0 + c];
  }

  const int wm = wave >> 2;  // 0..1 : 128 rows
  const int wn = wave & 3;   // 0..3 : 32 cols

  // ---- staging source (inverse-swizzled global addr; LDS dest linear) ----
  // swizzle: byte ^= ((row>>2)&3)<<5  <=>  elem ^= ((row>>2)&3)<<4
  const int mask2 = ((wave & 1) << 1) | (lane >> 5);      // = (row>>2)&3
  const int s_col = ((lane & 7) * 8) ^ (mask2 << 4);      // element col
  const int s_row = wave * 8 + (lane >> 3);               // row within 64-group
  const u16* a_base = Xb + (size_t)(row0 + s_row) * D_ + s_col;
  const u16* b_base = Wb + (size_t)(col0 + s_row) * D_ + s_col;
  const int lds_off = (wave * 8) * BK;                    // elems, wave-uniform

  // ---- swizzled LDS read offsets (elements) ----
  const int rmask = (lane >> 2) & 3;
  const int aq    = lane >> 4;
  const int ce0 = ((aq * 8)      ^ (rmask << 4));
  const int ce1 = ((aq * 8 + 32) ^ (rmask << 4));
  const int arow = (wm * 128 + (lane & 15)) * BK;
  const int brow = (wn * 32  + (lane & 15)) * BK;

  const f32x4 zero4 = {0.f, 0.f, 0.f, 0.f};
  f32x4 acc[8][2], part[8][2];
#pragma unroll
  for (int i = 0; i < 8; ++i)
#pragma unroll
    for (int j = 0; j < 2; ++j) { acc[i][j] = zero4; part[i][j] = zero4; }

  // ---- prologue: stage tiles 0 and 1 (both h=0) ----
#pragma unroll
  for (int i = 0; i < 4; ++i)
    GLOAD16(a_base + (size_t)(i * 64) * D_, &As[0][lds_off + i * 64 * BK]);
#pragma unroll
  for (int j = 0; j < 2; ++j)
    GLOAD16(b_base + (size_t)(j * 64) * D_, &Bs[0][lds_off + j * 64 * BK]);
#pragma unroll
  for (int i = 0; i < 4; ++i)
    GLOAD16(a_base + (size_t)(i * 64) * D_ + 64, &As[1][lds_off + i * 64 * BK]);
#pragma unroll
  for (int j = 0; j < 2; ++j)
    GLOAD16(b_base + (size_t)(j * 64) * D_ + 64, &Bs[1][lds_off + j * 64 * BK]);

  asm volatile("s_waitcnt vmcnt(6) lgkmcnt(0)" ::: "memory");
  __builtin_amdgcn_s_barrier();

  int buf = 0;
  for (int t = 0; t < NT; ++t) {
    const u16* Ab = &As[buf][0];
    const u16* Bb = &Bs[buf][0];
    const int t2 = t + 2;
    const int sbuf = (buf + 2 >= 3) ? buf - 1 : buf + 2;

    short8 af[8], bfr[2];

    // ============ phase 0 (kk=0) ============
#pragma unroll
    for (int fm = 0; fm < 8; ++fm)
      af[fm] = *(const short8*)&Ab[arow + fm * 16 * BK + ce0];
#pragma unroll
    for (int fn = 0; fn < 2; ++fn)
      bfr[fn] = *(const short8*)&Bb[brow + fn * 16 * BK + ce0];

    if (t2 < NT) {  // prefetch A of tile t+2
      const size_t koff = (size_t)((t2 & 15) * 64);
#pragma unroll
      for (int i = 0; i < 4; ++i)
        GLOAD16(a_base + (size_t)(i * 64) * D_ + koff,
                &As[sbuf][lds_off + i * 64 * BK]);
    }
    __builtin_amdgcn_s_barrier();
    __builtin_amdgcn_s_setprio(1);
#pragma unroll
    for (int fm = 0; fm < 8; ++fm) {
      part[fm][0] = __builtin_amdgcn_mfma_f32_16x16x32_bf16(
          af[fm], bfr[0], part[fm][0], 0, 0, 0);
      part[fm][1] = __builtin_amdgcn_mfma_f32_16x16x32_bf16(
          af[fm], bfr[1], part[fm][1], 0, 0, 0);
    }
    __builtin_amdgcn_s_setprio(0);
    __builtin_amdgcn_s_barrier();

    // ============ phase 1 (kk=1) ============
#pragma unroll
    for (int fm = 0; fm < 8; ++fm)
      af[fm] = *(const short8*)&Ab[arow + fm * 16 * BK + ce1];
#pragma unroll
    for (int fn = 0; fn < 2; ++fn)
      bfr[fn] = *(const short8*)&Bb[brow + fn * 16 * BK + ce1];

    if (t2 < NT) {  // prefetch B of tile t+2
      const size_t boff = ((size_t)(t2 >> 4) * O_) * D_ + (size_t)((t2 & 15) * 64);
#pragma unroll
      for (int j = 0; j < 2; ++j)
        GLOAD16(b_base + (size_t)(j * 64) * D_ + boff,
                &Bs[sbuf][lds_off + j * 64 * BK]);
    }
    __builtin_amdgcn_s_barrier();
    __builtin_amdgcn_s_setprio(1);
#pragma unroll
    for (int fm = 0; fm < 8; ++fm) {
      part[fm][0] = __builtin_amdgcn_mfma_f32_16x16x32_bf16(
          af[fm], bfr[0], part[fm][0], 0, 0, 0);
      part[fm][1] = __builtin_amdgcn_mfma_f32_16x16x32_bf16(
          af[fm], bfr[1], part[fm][1], 0, 0, 0);
    }
    __builtin_amdgcn_s_setprio(0);

    if (t < NT - 2) {
      asm volatile("s_waitcnt vmcnt(6)" ::: "memory");  // t+1 ready, t+2 in flight
    } else {
      asm volatile("s_waitcnt vmcnt(0)" ::: "memory");
    }
    __builtin_amdgcn_s_barrier();

    // ============ fold at end of each expert h ============
    if ((t & 15) == 15) {
      const int h = t >> 4;
      const float ebv0 = ebs[h][wn * 32 + (lane & 15)];
      const float ebv1 = ebs[h][wn * 32 + 16 + (lane & 15)];
#pragma unroll
      for (int fm = 0; fm < 8; ++fm) {
        const f32x4 gg = *(const f32x4*)&gs[h][wm * 128 + fm * 16 + (lane >> 4) * 4];
#pragma unroll
        for (int j = 0; j < 4; ++j) {
          acc[fm][0][j] += gg[j] * (part[fm][0][j] + ebv0);
          acc[fm][1][j] += gg[j] * (part[fm][1][j] + ebv1);
          part[fm][0][j] = 0.f;
          part[fm][1][j] = 0.f;
        }
      }
    }

    buf = (buf == 2) ? 0 : buf + 1;
  }

  // ---- epilogue: C/D layout col = lane&15, row = (lane>>4)*4 + j ----
  const int crow = row0 + wm * 128 + (lane >> 4) * 4;
  const int ccol = col0 + wn * 32 + (lane & 15);
#pragma unroll
  for (int fm = 0; fm < 8; ++fm)
#pragma unroll
    for (int fn = 0; fn < 2; ++fn)
#pragma unroll
      for (int j = 0; j < 4; ++j)
        out[(size_t)(crow + fm * 16 + j) * O_ + (ccol + fn * 16)] =
            acc[fm][fn][j];
}

// ---------------------------------------------------------------------------
extern "C" void kernel_launch(void* const* d_in, const int* in_sizes, int n_in,
                              void* d_out, int out_size, void* d_ws,
                              size_t ws_size, hipStream_t stream) {
  const float* x   = (const float*)d_in[0];
  const float* gw  = (const float*)d_in[1];
  const float* gb  = (const float*)d_in[2];
  const float* ew  = (const float*)d_in[3];
  const float* ebp = (const float*)d_in[4];
  float* out = (float*)d_out;

  u16*   x_bf = (u16*)d_ws;                                            // 16 MB
  u16*   w_bf = (u16*)((char*)d_ws + (size_t)BS_ * D_ * 2);            // 16 MB
  float* gbuf = (float*)((char*)d_ws + (size_t)BS_ * D_ * 2 +
                         (size_t)H_ * O_ * D_ * 2);                    // 256 KB

  gate_conv_kernel<<<BS_ / 4, 256, 0, stream>>>(x, gw, gb, x_bf, gbuf);
  convw_kernel<<<(H_ * O_ * D_) / 2048, 256, 0, stream>>>(ew, w_bf);
  moe_gemm_kernel<<<(BS_ / BM) * (O_ / BN), 512, 0, stream>>>(x_bf, w_bf, gbuf,
                                                              ebp, out);
}